// Round 8
// baseline (19.331 us; speedup 1.0000x reference)
//
#include <hip/hip_runtime.h>
#include <cmath>

#define H_ 128
#define W_ 128
#define P_ (H_ * W_)
#define NTX 16
#define NTY 16
#define NTILES (NTX * NTY)
#define CAP 512
#define VMAX 1344
#define MAGIC 0x5AFE5AFEu

struct Cam {
    float ex, ey, ez;
    float r00, r01, r02, r10, r11, r12, r20, r21, r22;
};

// Single kernel, NTILES+1 blocks x 512 threads.
// Blocks 0..255: transform all vertices into LDS (bit-identical expression),
//   bin faces to this tile in LDS, 8 waves raster stride-8 slices, wave 0
//   shades + reduces, publishes partials[t] (u64 atomicExch) + MAGIC flag.
// Block 256: spins on the 256 flags (device-coherent atomic reads), sums the
//   partials in the same fixed order/tree as the old finalize kernel (bit-
//   identical), writes out, resets flags for the next replay.
// Key=(depth_bits<<32)|global_f: u64 lex-min == exact jnp.argmin first-index
// tie-break (depth>0 always), so LDS append order is irrelevant.
__global__ __launch_bounds__(512) void render_all(
    const float* __restrict__ verts, const int* __restrict__ faces,
    int F, int V, Cam cam, const float* __restrict__ tex,
    const float* __restrict__ ref, unsigned long long* __restrict__ partials,
    unsigned int* __restrict__ flags, float* __restrict__ out) {
#pragma clang fp contract(off)
    int t = blockIdx.x;
    int tid = threadIdx.x;

    // ---- consumer block: deterministic final reduction ----
    if (t == NTILES) {
        if (tid >= 64) return;
        double v = 0.0;
        for (int k = 0; k < 4; ++k) {
            int i = tid * 4 + k;
            while (atomicAdd(&flags[i], 0u) != MAGIC)
                __builtin_amdgcn_s_sleep(2);
            unsigned long long bits = atomicAdd(&partials[i], 0ull);
            v += __longlong_as_double((long long)bits);
        }
        for (int off = 32; off > 0; off >>= 1) v += __shfl_xor(v, off);
        if (tid == 0) out[0] = (float)v;
        for (int k = 0; k < 4; ++k)
            atomicExch(&flags[tid * 4 + k], 0u);   // reset for next call
        return;
    }

    __shared__ int lcnt;
    __shared__ float lvx[VMAX], lvy[VMAX], lvz[VMAX];
    __shared__ int lfi[CAP];
    __shared__ float4 lrec[CAP * 3];
    __shared__ unsigned long long lbest[8 * 64];
    int mytx = t & (NTX - 1), myty = t >> 4;
    if (tid == 0) lcnt = 0;
    // ---- transform all vertices once (bit-identical expression) ----
    for (int v = tid; v < V; v += 512) {
        float vx = verts[v * 3 + 0];
        float vy = verts[v * 3 + 1];
        float vz = verts[v * 3 + 2];
        float dx = vx - cam.ex, dy = vy - cam.ey, dz = vz - cam.ez;
        lvx[v] = (dx * cam.r00 + dy * cam.r01) + dz * cam.r02;
        lvy[v] = (dx * cam.r10 + dy * cam.r11) + dz * cam.r12;
        lvz[v] = (dx * cam.r20 + dy * cam.r21) + dz * cam.r22;
    }
    __syncthreads();

    // ---- bin: cull faces to this tile, append records to LDS ----
    for (int f = tid; f < F; f += 512) {
        int i0 = faces[f * 3 + 0], i1 = faces[f * 3 + 1], i2 = faces[f * 3 + 2];
        float a0 = lvx[i0], a1 = lvy[i0];
        float b0 = lvx[i1], b1 = lvy[i1];
        float c0 = lvx[i2], c1 = lvy[i2];
        float area = (b0 - a0) * (c1 - a1) - (b1 - a1) * (c0 - a0);
        float ab = fabsf(area);
        if (ab < 1e-8f) continue;
        // Conservative pixel bbox (expanded 1 px to absorb f32 edge rounding).
        float minx = fminf(fminf(a0, b0), c0), maxx = fmaxf(fmaxf(a0, b0), c0);
        float miny = fminf(fminf(a1, b1), c1), maxy = fmaxf(fmaxf(a1, b1), c1);
        int colmin = (int)ceilf((minx + 1.0f) * 64.0f - 0.5f) - 1;
        int colmax = (int)floorf((maxx + 1.0f) * 64.0f - 0.5f) + 1;
        int rowmin = (int)ceilf((1.0f - maxy) * 64.0f - 0.5f) - 1;
        int rowmax = (int)floorf((1.0f - miny) * 64.0f - 0.5f) + 1;
        colmin = max(colmin, 0); colmax = min(colmax, W_ - 1);
        rowmin = max(rowmin, 0); rowmax = min(rowmax, H_ - 1);
        if (colmin > colmax || rowmin > rowmax) continue;
        if (mytx < (colmin >> 3) || mytx > (colmax >> 3) ||
            myty < (rowmin >> 3) || myty > (rowmax >> 3)) continue;
        int slot = atomicAdd(&lcnt, 1);
        if (slot < CAP) {
            lfi[slot] = f;
            lrec[slot * 3 + 0] = make_float4(a0, a1, b0, b1);
            lrec[slot * 3 + 1] = make_float4(c0, c1, lvz[i0], lvz[i1]);
            lrec[slot * 3 + 2] = make_float4(lvz[i2], area, 0.0f, 0.0f);
        }
    }
    __syncthreads();
    int n = min(lcnt, CAP);

    // ---- raster: 8 waves, stride-8 slices of the list ----
    int wv = tid >> 6, lane = tid & 63;
    int lx = lane & 7, ly = lane >> 3;
    int col = mytx * 8 + lx, row = myty * 8 + ly;
    int pid = row * W_ + col;
    float px = ((col + 0.5f) / 128.0f) * 2.0f - 1.0f;
    float py = 1.0f - ((row + 0.5f) / 128.0f) * 2.0f;
    unsigned long long best = ~0ull;
    for (int i = wv; i < n; i += 8) {
        float4 r0 = lrec[i * 3 + 0];
        float4 r1 = lrec[i * 3 + 1];
        float4 r2 = lrec[i * 3 + 2];
        float a0 = r0.x, a1 = r0.y, b0 = r0.z, b1 = r0.w;
        float c0 = r1.x, c1 = r1.y, z0 = r1.z, z1 = r1.w;
        float z2 = r2.x, sa = r2.y;
        float w0n = (c0 - b0) * (py - b1) - (c1 - b1) * (px - b0);
        float w1n = (a0 - c0) * (py - c1) - (a1 - c1) * (px - c0);
        float w2n = (b0 - a0) * (py - a1) - (b1 - a1) * (px - a0);
        bool ins;
        if (sa > 0.0f) ins = (w0n >= 0.0f) & (w1n >= 0.0f) & (w2n >= 0.0f);
        else           ins = (w0n <= 0.0f) & (w1n <= 0.0f) & (w2n <= 0.0f);
        if (ins) {
            float w0 = w0n / sa, w1 = w1n / sa, w2 = w2n / sa;
            float d = (w0 * z0 + w1 * z1) + w2 * z2;   // always > 0 here
            unsigned long long key =
                ((unsigned long long)__float_as_uint(d) << 32)
                | (unsigned)lfi[i];
            best = min(best, key);
        }
    }
    lbest[wv * 64 + lane] = best;
    __syncthreads();
    if (wv != 0) return;

    // ---- merge + shade (wave 0 only) ----
    unsigned long long key = best;
    for (int s = 1; s < 8; ++s) key = min(key, lbest[s * 64 + lane]);
    float bd = __uint_as_float((unsigned)(key >> 32));
    bool hit = bd < 5e9f;                  // miss -> NaN bits -> false
    int bestf = hit ? (int)(unsigned)(key & 0xffffffffu) : 0;
    // Winning face's 2D record straight from LDS (bit-identical values).
    int i0 = faces[bestf * 3 + 0], i1 = faces[bestf * 3 + 1],
        i2 = faces[bestf * 3 + 2];
    float a0 = lvx[i0], a1 = lvy[i0];
    float b0 = lvx[i1], b1 = lvy[i1];
    float c0 = lvx[i2], c1 = lvy[i2];
    float area = (b0 - a0) * (c1 - a1) - (b1 - a1) * (c0 - a0);
    float sa = (fabsf(area) < 1e-8f) ? 1e-8f : area;
    float u0 = ((c0 - b0) * (py - b1) - (c1 - b1) * (px - b0)) / sa;
    float u1 = ((a0 - c0) * (py - c1) - (a1 - c1) * (px - c0)) / sa;
    float u2 = ((b0 - a0) * (py - a1) - (b1 - a1) * (px - a0)) / sa;
    float w0 = fminf(fmaxf(u0, 0.0f), 1.0f);
    float w1 = fminf(fmaxf(u1, 0.0f), 1.0f);
    float w2 = fminf(fmaxf(u2, 0.0f), 1.0f);
    float ssum = ((w0 + w1) + w2) + 1e-8f;
    float n0 = w0 / ssum, n1 = w1 / ssum, n2 = w2 / ssum;
    float p0 = n0 * 3.0f, p1 = n1 * 3.0f, p2 = n2 * 3.0f;
    int l0 = (int)floorf(p0); l0 = min(max(l0, 0), 2);
    int l1 = (int)floorf(p1); l1 = min(max(l1, 0), 2);
    int l2 = (int)floorf(p2); l2 = min(max(l2, 0), 2);
    float fr0 = p0 - (float)l0;
    float fr1 = p1 - (float)l1;
    float fr2 = p2 - (float)l2;
    const float* tb = tex + (size_t)bestf * 192;
    float cr = 0.0f, cg = 0.0f, cb = 0.0f;
    for (int di = 0; di < 2; ++di)
        for (int dj = 0; dj < 2; ++dj)
            for (int dk = 0; dk < 2; ++dk) {
                float wx = di ? fr0 : (1.0f - fr0);
                float wy = dj ? fr1 : (1.0f - fr1);
                float wz = dk ? fr2 : (1.0f - fr2);
                float wgt = (wx * wy) * wz;
                int off = (((l0 + di) * 4 + (l1 + dj)) * 4 + (l2 + dk)) * 3;
                cr = cr + wgt * tanhf(tb[off + 0]);
                cg = cg + wgt * tanhf(tb[off + 1]);
                cb = cb + wgt * tanhf(tb[off + 2]);
            }
    double acc = 0.0;
    {
        float fc = hit ? cr : 0.0f;
        float d = fc - ref[0 * P_ + pid];
        acc += (double)(d * d);
        fc = hit ? cg : 0.0f;
        d = fc - ref[1 * P_ + pid];
        acc += (double)(d * d);
        fc = hit ? cb : 0.0f;
        d = fc - ref[2 * P_ + pid];
        acc += (double)(d * d);
    }
    for (int off = 32; off > 0; off >>= 1) acc += __shfl_down(acc, off);
    if (lane == 0) {
        atomicExch(&partials[t],
                   (unsigned long long)__double_as_longlong(acc));
        __threadfence();
        atomicExch(&flags[t], MAGIC);
    }
}

extern "C" void kernel_launch(void* const* d_in, const int* in_sizes, int n_in,
                              void* d_out, int out_size, void* d_ws, size_t ws_size,
                              hipStream_t stream) {
    const float* vertices = (const float*)d_in[0];
    const float* textures = (const float*)d_in[1];
    const float* image_ref = (const float*)d_in[2];
    const int* faces = (const int*)d_in[3];
    int V = in_sizes[0] / 3;
    int F = in_sizes[3] / 3;

    // Camera computed on host in f32, mirroring reference _look_at exactly.
    float az = (float)(90.0 * M_PI / 180.0);
    float el = 0.0f;
    float ce = cosf(el), se = sinf(el);
    float sz = sinf(az), cz = cosf(az);
    const float DIST = 2.732f;
    float ex = DIST * (ce * sz);
    float ey = DIST * se;
    float ez = DIST * (-(ce * cz));
    float nrm = sqrtf((ex * ex + ey * ey) + ez * ez);
    float z0 = -ex / nrm, z1 = -ey / nrm, z2 = -ez / nrm;
    float x0 = 1.0f * z2 - 0.0f * z1;
    float x1 = 0.0f * z0 - 0.0f * z2;
    float x2 = 0.0f * z1 - 1.0f * z0;
    float xn = sqrtf((x0 * x0 + x1 * x1) + x2 * x2);
    x0 /= xn; x1 /= xn; x2 /= xn;
    float y0 = z1 * x2 - z2 * x1;
    float y1 = z2 * x0 - z0 * x2;
    float y2 = z0 * x1 - z1 * x0;
    Cam cam{ex, ey, ez, x0, x1, x2, y0, y1, y2, z0, z1, z2};

    // Workspace: partials(256 u64) | flags(256 u32)
    unsigned long long* partials = (unsigned long long*)d_ws;
    unsigned int* flags = (unsigned int*)((char*)d_ws + 256 * 8);

    hipLaunchKernelGGL(render_all, dim3(NTILES + 1), dim3(512), 0, stream,
                       vertices, faces, F, V, cam, textures, image_ref,
                       partials, flags, (float*)d_out);
}

// Round 9
// 17.788 us; speedup vs baseline: 1.0867x; 1.0867x over previous
//
#include <hip/hip_runtime.h>
#include <cmath>

#define H_ 128
#define W_ 128
#define P_ (H_ * W_)
#define NTX 16
#define NTY 16
#define NTILES (NTX * NTY)
#define CAP 512
#define VMAX 1344

struct Cam {
    float ex, ey, ez;
    float r00, r01, r02, r10, r11, r12, r20, r21, r22;
};

// One 512-thread block per 8x8 tile. Transform all vertices into LDS once
// (bit-identical expression), bin faces to this tile in LDS, 8 waves raster
// stride-8 slices, wave 0 shades + reduces, plain-stores partials[t].
// Key=(depth_bits<<32)|global_f: u64 lex-min == exact jnp.argmin first-index
// tie-break (depth>0 always), so LDS append order is irrelevant.
__global__ __launch_bounds__(512) void render_all(
    const float* __restrict__ verts, const int* __restrict__ faces,
    int F, int V, Cam cam, const float* __restrict__ tex,
    const float* __restrict__ ref, double* __restrict__ partials) {
#pragma clang fp contract(off)
    __shared__ int lcnt;
    __shared__ float lvx[VMAX], lvy[VMAX], lvz[VMAX];
    __shared__ int lfi[CAP];
    __shared__ float4 lrec[CAP * 3];
    __shared__ unsigned long long lbest[8 * 64];
    int t = blockIdx.x;
    int tid = threadIdx.x;
    int mytx = t & (NTX - 1), myty = t >> 4;
    if (tid == 0) lcnt = 0;
    // ---- transform all vertices once (bit-identical expression) ----
    for (int v = tid; v < V; v += 512) {
        float vx = verts[v * 3 + 0];
        float vy = verts[v * 3 + 1];
        float vz = verts[v * 3 + 2];
        float dx = vx - cam.ex, dy = vy - cam.ey, dz = vz - cam.ez;
        lvx[v] = (dx * cam.r00 + dy * cam.r01) + dz * cam.r02;
        lvy[v] = (dx * cam.r10 + dy * cam.r11) + dz * cam.r12;
        lvz[v] = (dx * cam.r20 + dy * cam.r21) + dz * cam.r22;
    }
    __syncthreads();

    // ---- bin: cull faces to this tile, append records to LDS ----
    for (int f = tid; f < F; f += 512) {
        int i0 = faces[f * 3 + 0], i1 = faces[f * 3 + 1], i2 = faces[f * 3 + 2];
        float a0 = lvx[i0], a1 = lvy[i0];
        float b0 = lvx[i1], b1 = lvy[i1];
        float c0 = lvx[i2], c1 = lvy[i2];
        float area = (b0 - a0) * (c1 - a1) - (b1 - a1) * (c0 - a0);
        float ab = fabsf(area);
        if (ab < 1e-8f) continue;
        // Conservative pixel bbox (expanded 1 px to absorb f32 edge rounding).
        float minx = fminf(fminf(a0, b0), c0), maxx = fmaxf(fmaxf(a0, b0), c0);
        float miny = fminf(fminf(a1, b1), c1), maxy = fmaxf(fmaxf(a1, b1), c1);
        int colmin = (int)ceilf((minx + 1.0f) * 64.0f - 0.5f) - 1;
        int colmax = (int)floorf((maxx + 1.0f) * 64.0f - 0.5f) + 1;
        int rowmin = (int)ceilf((1.0f - maxy) * 64.0f - 0.5f) - 1;
        int rowmax = (int)floorf((1.0f - miny) * 64.0f - 0.5f) + 1;
        colmin = max(colmin, 0); colmax = min(colmax, W_ - 1);
        rowmin = max(rowmin, 0); rowmax = min(rowmax, H_ - 1);
        if (colmin > colmax || rowmin > rowmax) continue;
        if (mytx < (colmin >> 3) || mytx > (colmax >> 3) ||
            myty < (rowmin >> 3) || myty > (rowmax >> 3)) continue;
        int slot = atomicAdd(&lcnt, 1);
        if (slot < CAP) {
            lfi[slot] = f;
            lrec[slot * 3 + 0] = make_float4(a0, a1, b0, b1);
            lrec[slot * 3 + 1] = make_float4(c0, c1, lvz[i0], lvz[i1]);
            lrec[slot * 3 + 2] = make_float4(lvz[i2], area, 0.0f, 0.0f);
        }
    }
    __syncthreads();
    int n = min(lcnt, CAP);

    // ---- raster: 8 waves, stride-8 slices of the list ----
    int wv = tid >> 6, lane = tid & 63;
    int lx = lane & 7, ly = lane >> 3;
    int col = mytx * 8 + lx, row = myty * 8 + ly;
    int pid = row * W_ + col;
    float px = ((col + 0.5f) / 128.0f) * 2.0f - 1.0f;
    float py = 1.0f - ((row + 0.5f) / 128.0f) * 2.0f;
    unsigned long long best = ~0ull;
    for (int i = wv; i < n; i += 8) {
        float4 r0 = lrec[i * 3 + 0];
        float4 r1 = lrec[i * 3 + 1];
        float4 r2 = lrec[i * 3 + 2];
        float a0 = r0.x, a1 = r0.y, b0 = r0.z, b1 = r0.w;
        float c0 = r1.x, c1 = r1.y, z0 = r1.z, z1 = r1.w;
        float z2 = r2.x, sa = r2.y;
        float w0n = (c0 - b0) * (py - b1) - (c1 - b1) * (px - b0);
        float w1n = (a0 - c0) * (py - c1) - (a1 - c1) * (px - c0);
        float w2n = (b0 - a0) * (py - a1) - (b1 - a1) * (px - a0);
        bool ins;
        if (sa > 0.0f) ins = (w0n >= 0.0f) & (w1n >= 0.0f) & (w2n >= 0.0f);
        else           ins = (w0n <= 0.0f) & (w1n <= 0.0f) & (w2n <= 0.0f);
        if (ins) {
            float w0 = w0n / sa, w1 = w1n / sa, w2 = w2n / sa;
            float d = (w0 * z0 + w1 * z1) + w2 * z2;   // always > 0 here
            unsigned long long key =
                ((unsigned long long)__float_as_uint(d) << 32)
                | (unsigned)lfi[i];
            best = min(best, key);
        }
    }
    lbest[wv * 64 + lane] = best;
    __syncthreads();
    if (wv != 0) return;

    // ---- merge + shade (wave 0 only) ----
    unsigned long long key = best;
    for (int s = 1; s < 8; ++s) key = min(key, lbest[s * 64 + lane]);
    float bd = __uint_as_float((unsigned)(key >> 32));
    bool hit = bd < 5e9f;                  // miss -> NaN bits -> false
    int bestf = hit ? (int)(unsigned)(key & 0xffffffffu) : 0;
    // Winning face's 2D record straight from LDS (bit-identical values).
    int i0 = faces[bestf * 3 + 0], i1 = faces[bestf * 3 + 1],
        i2 = faces[bestf * 3 + 2];
    float a0 = lvx[i0], a1 = lvy[i0];
    float b0 = lvx[i1], b1 = lvy[i1];
    float c0 = lvx[i2], c1 = lvy[i2];
    float area = (b0 - a0) * (c1 - a1) - (b1 - a1) * (c0 - a0);
    float sa = (fabsf(area) < 1e-8f) ? 1e-8f : area;
    float u0 = ((c0 - b0) * (py - b1) - (c1 - b1) * (px - b0)) / sa;
    float u1 = ((a0 - c0) * (py - c1) - (a1 - c1) * (px - c0)) / sa;
    float u2 = ((b0 - a0) * (py - a1) - (b1 - a1) * (px - a0)) / sa;
    float w0 = fminf(fmaxf(u0, 0.0f), 1.0f);
    float w1 = fminf(fmaxf(u1, 0.0f), 1.0f);
    float w2 = fminf(fmaxf(u2, 0.0f), 1.0f);
    float ssum = ((w0 + w1) + w2) + 1e-8f;
    float n0 = w0 / ssum, n1 = w1 / ssum, n2 = w2 / ssum;
    float p0 = n0 * 3.0f, p1 = n1 * 3.0f, p2 = n2 * 3.0f;
    int l0 = (int)floorf(p0); l0 = min(max(l0, 0), 2);
    int l1 = (int)floorf(p1); l1 = min(max(l1, 0), 2);
    int l2 = (int)floorf(p2); l2 = min(max(l2, 0), 2);
    float fr0 = p0 - (float)l0;
    float fr1 = p1 - (float)l1;
    float fr2 = p2 - (float)l2;
    const float* tb = tex + (size_t)bestf * 192;
    float cr = 0.0f, cg = 0.0f, cb = 0.0f;
    for (int di = 0; di < 2; ++di)
        for (int dj = 0; dj < 2; ++dj)
            for (int dk = 0; dk < 2; ++dk) {
                float wx = di ? fr0 : (1.0f - fr0);
                float wy = dj ? fr1 : (1.0f - fr1);
                float wz = dk ? fr2 : (1.0f - fr2);
                float wgt = (wx * wy) * wz;
                int off = (((l0 + di) * 4 + (l1 + dj)) * 4 + (l2 + dk)) * 3;
                cr = cr + wgt * tanhf(tb[off + 0]);
                cg = cg + wgt * tanhf(tb[off + 1]);
                cb = cb + wgt * tanhf(tb[off + 2]);
            }
    double acc = 0.0;
    {
        float fc = hit ? cr : 0.0f;
        float d = fc - ref[0 * P_ + pid];
        acc += (double)(d * d);
        fc = hit ? cg : 0.0f;
        d = fc - ref[1 * P_ + pid];
        acc += (double)(d * d);
        fc = hit ? cb : 0.0f;
        d = fc - ref[2 * P_ + pid];
        acc += (double)(d * d);
    }
    for (int off = 32; off > 0; off >>= 1) acc += __shfl_down(acc, off);
    if (lane == 0) partials[t] = acc;
}

__global__ __launch_bounds__(64) void finalize(
    const double* __restrict__ partials, float* __restrict__ out) {
    double v = 0.0;
    for (int k = 0; k < 4; ++k) v += partials[threadIdx.x * 4 + k];
    for (int off = 32; off > 0; off >>= 1) v += __shfl_xor(v, off);
    if (threadIdx.x == 0) out[0] = (float)v;
}

extern "C" void kernel_launch(void* const* d_in, const int* in_sizes, int n_in,
                              void* d_out, int out_size, void* d_ws, size_t ws_size,
                              hipStream_t stream) {
    const float* vertices = (const float*)d_in[0];
    const float* textures = (const float*)d_in[1];
    const float* image_ref = (const float*)d_in[2];
    const int* faces = (const int*)d_in[3];
    int V = in_sizes[0] / 3;
    int F = in_sizes[3] / 3;

    // Camera computed on host in f32, mirroring reference _look_at exactly.
    float az = (float)(90.0 * M_PI / 180.0);
    float el = 0.0f;
    float ce = cosf(el), se = sinf(el);
    float sz = sinf(az), cz = cosf(az);
    const float DIST = 2.732f;
    float ex = DIST * (ce * sz);
    float ey = DIST * se;
    float ez = DIST * (-(ce * cz));
    float nrm = sqrtf((ex * ex + ey * ey) + ez * ez);
    float z0 = -ex / nrm, z1 = -ey / nrm, z2 = -ez / nrm;
    float x0 = 1.0f * z2 - 0.0f * z1;
    float x1 = 0.0f * z0 - 0.0f * z2;
    float x2 = 0.0f * z1 - 1.0f * z0;
    float xn = sqrtf((x0 * x0 + x1 * x1) + x2 * x2);
    x0 /= xn; x1 /= xn; x2 /= xn;
    float y0 = z1 * x2 - z2 * x1;
    float y1 = z2 * x0 - z0 * x2;
    float y2 = z0 * x1 - z1 * x0;
    Cam cam{ex, ey, ez, x0, x1, x2, y0, y1, y2, z0, z1, z2};

    double* partials = (double*)d_ws;

    hipLaunchKernelGGL(render_all, dim3(NTILES), dim3(512), 0, stream,
                       vertices, faces, F, V, cam, textures, image_ref,
                       partials);
    hipLaunchKernelGGL(finalize, dim3(1), dim3(64), 0, stream,
                       partials, (float*)d_out);
}